// Round 4
// baseline (311.790 us; speedup 1.0000x reference)
//
#include <hip/hip_runtime.h>
#include <stdint.h>

typedef unsigned short u16;
typedef __bf16  bf16x8 __attribute__((ext_vector_type(8)));
typedef float   f32x4  __attribute__((ext_vector_type(4)));
typedef unsigned short us8 __attribute__((ext_vector_type(8)));

__device__ __forceinline__ u16 f2bf(float f) {
    union { float f; unsigned u; } c; c.f = f;
    unsigned r = c.u + 0x7fffu + ((c.u >> 16) & 1u);   // RNE, finite inputs
    return (u16)(r >> 16);
}
__device__ __forceinline__ float bf2f(u16 b) {
    union { unsigned u; float f; } c; c.u = ((unsigned)b) << 16; return c.f;
}

// async 16B global->LDS. Generic LDS ptr: low 32 bits are the LDS offset on gfx9+.
__device__ __forceinline__ void g2l16(const u16* g, u16* l) {
    __builtin_amdgcn_global_load_lds(
        (__attribute__((address_space(1))) void*)(uintptr_t)g,
        (__attribute__((address_space(3))) void*)(uint32_t)(uintptr_t)l,
        16, 0, 0);
}

// ---------------------------------------------------------------------------
// NT GEMM core (bf16 in, fp32 acc): C[m,n] = sum_k A[m,k]*B[n,k]
//   (+ bias[m]) (+ wRbA[m]*svec[n] rank-1 term if EPI).
// A,B row-major bf16, ld == K. Tile TM x 128, BK=64, 256 thr = 4 waves (2x2).
// LDS XOR-swizzle: physical 16B chunk = logical ^ (row&7) -> conflict-free.
// SMAXB: B is RAW logits; staging applies y = f2bf(exp(v - m_row) * inv_row)
// using precomputed per-row stats (bit-identical to materialized softmax).
// B then reg-staged (load->exp->ds_write_b128, same swizzled slots).
// ---------------------------------------------------------------------------
template <int TM, bool HAS_BIAS, bool OUT_F32, bool EPI, bool SMAXB>
__device__ __forceinline__ void gemm_core(
    const u16* __restrict__ Ab, const u16* __restrict__ Bb, void* __restrict__ C,
    const float* __restrict__ bias, int N, int K, long cbase, int m0, int n0,
    const float* __restrict__ svec, const float* __restrict__ wRbA,
    const float2* __restrict__ bstats)
{
    constexpr int MI = TM / 32;
    constexpr int NA = TM / 32;
    __shared__ __align__(16) u16 As[TM * 64];
    __shared__ __align__(16) u16 Bs[128 * 64];

    const int t = threadIdx.x;
    const int w = t >> 6, lane = t & 63;
    const int wr = w >> 1, wc = w & 1;

    f32x4 acc[MI][4];
    const f32x4 zero = {0.f, 0.f, 0.f, 0.f};
#pragma unroll
    for (int i = 0; i < MI; ++i)
#pragma unroll
        for (int j = 0; j < 4; ++j) acc[i][j] = zero;

    int  aslot[NA]; long aoff[NA];
#pragma unroll
    for (int i = 0; i < NA; ++i) {
        const int s   = i * 256 + t;
        const int row = s >> 3;
        const int col = ((s & 7) ^ (row & 7)) * 8;
        aslot[i] = s * 8;
        aoff[i]  = (long)(m0 + row) * K + col;
    }
    int  bslot[4]; long boff[4];
    float2 bst[4];
#pragma unroll
    for (int i = 0; i < 4; ++i) {
        const int s   = i * 256 + t;
        const int row = s >> 3;
        const int col = ((s & 7) ^ (row & 7)) * 8;
        bslot[i] = s * 8;
        boff[i]  = (long)(n0 + row) * K + col;
        if (SMAXB) bst[i] = bstats[n0 + row];
    }

    const int fr = lane & 15;
    const int q  = lane >> 4;
    const int o0 = ((q ^ (fr & 7)) * 8);   // kh=0; kh=1 is o0 ^ 32
    const u16* fa = &As[(wr * (TM / 2) + fr) * 64];
    const u16* fb = &Bs[(wc * 64 + fr) * 64];

    for (int k0 = 0; k0 < K; k0 += 64) {
#pragma unroll
        for (int i = 0; i < NA; ++i) g2l16(Ab + aoff[i] + k0, &As[aslot[i]]);
        if (SMAXB) {
#pragma unroll
            for (int i = 0; i < 4; ++i) {
                us8 raw = *(const us8*)(Bb + boff[i] + k0);
                us8 o;
#pragma unroll
                for (int j = 0; j < 8; ++j)
                    o[j] = f2bf(__expf(bf2f(raw[j]) - bst[i].x) * bst[i].y);
                *(us8*)&Bs[bslot[i]] = o;
            }
        } else {
#pragma unroll
            for (int i = 0; i < 4; ++i) g2l16(Bb + boff[i] + k0, &Bs[bslot[i]]);
        }
        __syncthreads();

#pragma unroll
        for (int kh = 0; kh < 2; ++kh) {
            const int o = o0 ^ (kh * 32);
            bf16x8 af[MI], bv[4];
#pragma unroll
            for (int mi = 0; mi < MI; ++mi) af[mi] = *(const bf16x8*)(fa + mi * 1024 + o);
#pragma unroll
            for (int ni = 0; ni < 4; ++ni)  bv[ni] = *(const bf16x8*)(fb + ni * 1024 + o);
#pragma unroll
            for (int mi = 0; mi < MI; ++mi)
#pragma unroll
                for (int ni = 0; ni < 4; ++ni)
                    acc[mi][ni] = __builtin_amdgcn_mfma_f32_16x16x32_bf16(
                        af[mi], bv[ni], acc[mi][ni], 0, 0, 0);
        }
        __syncthreads();
    }

    // C/D layout (m89-verified): col = lane&15, row = (lane>>4)*4 + reg
    const int ccol  = n0 + wc * 64 + fr;
    const int crow0 = m0 + wr * (TM / 2) + (lane >> 4) * 4;
    float se[4];
    if (EPI) {
#pragma unroll
        for (int ni = 0; ni < 4; ++ni) se[ni] = svec[ccol + ni * 16];
    }
#pragma unroll
    for (int mi = 0; mi < MI; ++mi) {
#pragma unroll
        for (int r = 0; r < 4; ++r) {
            const int row = crow0 + mi * 16 + r;
            float add = HAS_BIAS ? bias[row] : 0.f;
            float rk  = EPI ? wRbA[row] : 0.f;
#pragma unroll
            for (int ni = 0; ni < 4; ++ni) {
                float v = acc[mi][ni][r] + add;
                if (EPI) v += rk * se[ni];
                const long idx = cbase + (long)row * N + ccol + ni * 16;
                if (OUT_F32) ((float*)C)[idx] = v;
                else         ((u16*)C)[idx]   = f2bf(v);
            }
        }
    }
}

// 3D-grid variant (GEMM1): blockIdx = (n-blk, m-blk, batch)
template <int TM, bool HAS_BIAS, bool OUT_F32>
__global__ __launch_bounds__(256) void gemm_nt(
    const u16* __restrict__ A, const u16* __restrict__ B, void* __restrict__ C,
    const float* __restrict__ bias, int N, int K, long sA, long sB, long sC)
{
    const int bz = blockIdx.z;
    gemm_core<TM, HAS_BIAS, OUT_F32, false, false>(
        A + (long)bz * sA, B + (long)bz * sB, C, bias, N, K,
        (long)bz * sC, blockIdx.y * TM, blockIdx.x * 128, nullptr, nullptr, nullptr);
}

// 1D-grid XCD-swizzled variant (GEMM4 / GEMM6)
template <int TM, bool HAS_BIAS, bool OUT_F32, bool EPI, bool SMAXB>
__global__ __launch_bounds__(256) void gemm_nt_swz(
    const u16* __restrict__ A, const u16* __restrict__ B, void* __restrict__ C,
    const float* __restrict__ bias, int N, int K, long sA, long sB, long sC,
    int bxn, int bpb, const float* __restrict__ s_all,
    const float* __restrict__ wRbA, const float2* __restrict__ stats_all)
{
    const int blk  = blockIdx.x;
    const int xcd  = blk & 7;
    const int slot = blk >> 3;
    const int b    = xcd + 8 * (slot / bpb);
    const int wi   = slot % bpb;
    const int bx   = wi % bxn;
    const int by   = wi / bxn;
    gemm_core<TM, HAS_BIAS, OUT_F32, EPI, SMAXB>(
        A + (long)b * sA, B + (long)b * sB, C, bias, N, K,
        (long)b * sC, by * TM, bx * 128,
        EPI ? s_all + (long)b * 1024 : nullptr, wRbA,
        SMAXB ? stats_all + (long)b * 1024 : nullptr);
}

// ---------------------------------------------------------------------------
// GEMM2 (Y = Wcat * Xt^T + bcat), 256x256 tile, 512 thr = 8 waves (2x4),
// BK=32, 4 LDS buffers (128 KiB), 2-tiles-ahead prefetch, counted vmcnt(4).
// v4: core identical to v3 (schedule variants v1-v3 measured flat, 64-66 µs,
// MfmaUtil ~32% -> schedule is not the limiter). NEW: batch-colocating XCD
// launch map — all 24 blocks of one batch on one XCD (1D grid 768 = 8 x 96,
// bijective), so the batch's Xt panel (1 MB) + Wcat (1.5 MB) stay in that
// XCD's 4 MB L2 across all m-block re-reads.
// ---------------------------------------------------------------------------
__global__ __launch_bounds__(512) void gemm2_y(
    const u16* __restrict__ A,      // Wcat [1536,512]
    const u16* __restrict__ B,      // Xt   [b][1024,512]
    u16* __restrict__ C,            // Y    [b][1536,1024]
    const float* __restrict__ bias) // bcat [1536]
{
    constexpr int K    = 512;
    constexpr int NT   = K / 32;          // 16 K-tiles
    constexpr int AREG = 256 * 32;        // u16 per operand region (8192)
    constexpr int BUFQ = 2 * AREG;        // u16 per buffer (A+B)
    __shared__ __align__(16) u16 lds[4 * BUFQ];   // 128 KiB

    // batch-colocated XCD map: xcd = blk&7 (dispatch heuristic), 96 slots/XCD,
    // 4 batches/XCD x 24 tile-blocks/batch
    const int blk  = blockIdx.x;
    const int xcd  = blk & 7;
    const int slot = blk >> 3;
    const int bz   = xcd + 8 * (slot / 24);
    const int wi   = slot % 24;
    const int m0   = (wi >> 2) * 256;     // 6 m-blocks
    const int n0   = (wi & 3) * 256;      // 4 n-blocks

    const u16* Ab = A;
    const u16* Bb = B + (long)bz * (1024 * 512);
    u16*       Cb = C + (long)bz * ((long)1536 * 1024);

    const int t    = threadIdx.x;
    const int w    = t >> 6, lane = t & 63;
    const int wr   = w >> 2, wc = w & 3;          // wave grid 2(M) x 4(N)
    const int fr   = lane & 15, q = lane >> 4;

    // ---- staging map: 1024 16B-chunks per operand per K-tile; 2/thread ----
    int  aslot[2]; long agoff[2], bgoff[2];
#pragma unroll
    for (int i = 0; i < 2; ++i) {
        const int ci  = i * 512 + t;
        const int row = ci >> 2;
        const int gc  = (ci & 3) ^ ((row >> 1) & 3);   // inverse == forward (XOR)
        aslot[i] = ci * 8;                             // linear u16 LDS slot
        agoff[i] = (long)(m0 + row) * K + gc * 8;
        bgoff[i] = (long)(n0 + row) * K + gc * 8;
    }

    // ---- fragment read offsets (u16): row*32 + chunk*8 ----
    const int rchunk = (q ^ ((fr >> 1) & 3)) * 8;
    const int abase  = (wr * 128 + fr) * 32 + rchunk;   // + mi*512
    const int bbase  = (wc * 64  + fr) * 32 + rchunk;   // + ni*512

    f32x4 acc[8][4];
    const f32x4 zero = {0.f, 0.f, 0.f, 0.f};
#pragma unroll
    for (int i = 0; i < 8; ++i)
#pragma unroll
        for (int j = 0; j < 4; ++j) acc[i][j] = zero;

    // ---- prologue: stage tiles 0 and 1 (A0,B0,A1,B1 -> 8 loads/thread) ----
#pragma unroll
    for (int i = 0; i < 2; ++i) g2l16(Ab + agoff[i],        &lds[aslot[i]]);
#pragma unroll
    for (int i = 0; i < 2; ++i) g2l16(Bb + bgoff[i],        &lds[AREG + aslot[i]]);
#pragma unroll
    for (int i = 0; i < 2; ++i) g2l16(Ab + agoff[i] + 32,   &lds[BUFQ + aslot[i]]);
#pragma unroll
    for (int i = 0; i < 2; ++i) g2l16(Bb + bgoff[i] + 32,   &lds[BUFQ + AREG + aslot[i]]);
    asm volatile("s_waitcnt vmcnt(4)" ::: "memory");   // tile 0 landed; tile 1 in flight
    __builtin_amdgcn_s_barrier();
    asm volatile("" ::: "memory");                     // no hoists above barrier

#pragma unroll
    for (int kt = 0; kt < NT; ++kt) {
        const u16* Abuf = &lds[(kt & 3) * BUFQ];           // constexpr (unrolled)
        const u16* Bbuf = Abuf + AREG;
        u16* dst = &lds[((kt + 2) & 3) * BUFQ];
        const long kg = (long)(kt + 2) * 32;

        // ---- fat region: reads + stage + MFMA, compiler-scheduled ----
        bf16x8 av[8], bv[4];
#pragma unroll
        for (int mi = 0; mi < 8; ++mi) av[mi] = *(const bf16x8*)(Abuf + abase + mi * 512);
#pragma unroll
        for (int ni = 0; ni < 4; ++ni) bv[ni] = *(const bf16x8*)(Bbuf + bbase + ni * 512);
        if (kt + 2 < NT) {                                 // constexpr (unrolled)
#pragma unroll
            for (int i = 0; i < 2; ++i) g2l16(Ab + agoff[i] + kg, dst + aslot[i]);
#pragma unroll
            for (int i = 0; i < 2; ++i) g2l16(Bb + bgoff[i] + kg, dst + AREG + aslot[i]);
        }
#pragma unroll
        for (int mi = 0; mi < 8; ++mi)
#pragma unroll
            for (int ni = 0; ni < 4; ++ni)
                acc[mi][ni] = __builtin_amdgcn_mfma_f32_16x16x32_bf16(
                    av[mi], bv[ni], acc[mi][ni], 0, 0, 0);

        // ---- tile boundary: counted wait (tile kt+1 landed; kt+2 in flight) ----
        if (kt + 1 < NT) {
            if (kt + 2 < NT) asm volatile("s_waitcnt vmcnt(4)" ::: "memory");
            else             asm volatile("s_waitcnt vmcnt(0)" ::: "memory");
            __builtin_amdgcn_s_barrier();
            asm volatile("" ::: "memory");                 // no hoists above barrier
        }
    }

    // ---- epilogue: col = lane&15, row = (lane>>4)*4 + reg ----
    const int ccol  = n0 + wc * 64 + fr;
    const int crow0 = m0 + wr * 128 + q * 4;
#pragma unroll
    for (int mi = 0; mi < 8; ++mi) {
#pragma unroll
        for (int r = 0; r < 4; ++r) {
            const int row = crow0 + mi * 16 + r;
            const float add = bias[row];
#pragma unroll
            for (int ni = 0; ni < 4; ++ni)
                Cb[(long)row * 1024 + ccol + ni * 16] = f2bf(acc[mi][ni][r] + add);
        }
    }
}

// ---------------------------------------------------------------------------
// x fp32 [b,512,1024] -> Xt bf16 [b,1024,512] (cast + transpose, 64x64 tiles)
// ---------------------------------------------------------------------------
__global__ __launch_bounds__(256) void cast_transpose_x(
    const float* __restrict__ in, u16* __restrict__ out)
{
    __shared__ u16 tile[64][68];
    const int bz = blockIdx.z;
    const float* ip = in  + (long)bz * (512 * 1024);
    u16*         op = out + (long)bz * (1024 * 512);
    const int c0 = blockIdx.x * 64;
    const int r0 = blockIdx.y * 64;
    const int tx = threadIdx.x & 15;
    const int ty = threadIdx.x >> 4;
#pragma unroll
    for (int p = 0; p < 4; ++p) {
        const int row = ty + 16 * p;
        float4 v = *(const float4*)(ip + (long)(r0 + row) * 1024 + c0 + 4 * tx);
        ushort4 o;
        o.x = f2bf(v.x); o.y = f2bf(v.y); o.z = f2bf(v.z); o.w = f2bf(v.w);
        *(ushort4*)&tile[row][4 * tx] = o;
    }
    __syncthreads();
#pragma unroll
    for (int p = 0; p < 4; ++p) {
        const int orow = ty + 16 * p;
        ushort4 o;
        o.x = tile[4 * tx + 0][orow];
        o.y = tile[4 * tx + 1][orow];
        o.z = tile[4 * tx + 2][orow];
        o.w = tile[4 * tx + 3][orow];
        *(ushort4*)&op[(long)(c0 + orow) * 512 + r0 + 4 * tx] = o;
    }
}

// ---------------------------------------------------------------------------
// Vm RAW [d,n] -> attnV^T = Vt [n,d] per batch (softmax applied on the fly
// from rowstats), PLUS column-sum s[b,n] += sum_d attnV[d,n] (s pre-zeroed).
// Bit-identical to materialized softmax: f2bf(exp(v - m_row) * inv_row).
// ---------------------------------------------------------------------------
__global__ __launch_bounds__(256) void transpose_colsum(
    const u16* __restrict__ in, u16* __restrict__ out, float* __restrict__ s,
    long sIn, long sOut, const float2* __restrict__ stats_all)
{
    __shared__ u16 tile[64][68];
    const int bz = blockIdx.z;
    const u16* ip = in  + (long)bz * sIn;
    u16*       op = out + (long)bz * sOut;
    const int c0 = blockIdx.x * 64;   // n
    const int r0 = blockIdx.y * 64;   // d
    const int t  = threadIdx.x;
    const int tx = t & 15;
    const int ty = t >> 4;
#pragma unroll
    for (int p = 0; p < 4; ++p) {
        const int row = ty + 16 * p;
        const float2 st = stats_all[(long)bz * 1024 + 512 + r0 + row];
        ushort4 v = *(const ushort4*)(ip + (long)(r0 + row) * 1024 + c0 + 4 * tx);
        ushort4 o;
        o.x = f2bf(__expf(bf2f(v.x) - st.x) * st.y);
        o.y = f2bf(__expf(bf2f(v.y) - st.x) * st.y);
        o.z = f2bf(__expf(bf2f(v.z) - st.x) * st.y);
        o.w = f2bf(__expf(bf2f(v.w) - st.x) * st.y);
        *(ushort4*)&tile[row][4 * tx] = o;
    }
    __syncthreads();
#pragma unroll
    for (int p = 0; p < 4; ++p) {
        const int orow = ty + 16 * p;
        ushort4 o;
        o.x = tile[4 * tx + 0][orow];
        o.y = tile[4 * tx + 1][orow];
        o.z = tile[4 * tx + 2][orow];
        o.w = tile[4 * tx + 3][orow];
        *(ushort4*)&op[(long)(c0 + orow) * 512 + r0 + 4 * tx] = o;
    }
    if (t < 64) {
        float a = 0.f;
#pragma unroll 8
        for (int d = 0; d < 64; ++d) a += bf2f(tile[d][t]);
        atomicAdd(&s[(long)bz * 1024 + c0 + t], a);
    }
}

// ---------------------------------------------------------------------------
// weights: wB/wV -> Wcat rows 512..1535 (bf16); wR -> wRb; wA -> wAtb (bf16,
// transposed); biases -> bcat fp32 [1536] with rows 0..511 = 0 (A' has no
// bias; it's folded into the rank-1 epilogue term).
// ---------------------------------------------------------------------------
__global__ __launch_bounds__(256) void cast_weights(
    const float* __restrict__ wA, const float* __restrict__ wB,
    const float* __restrict__ wV, const float* __restrict__ wR,
    const float* __restrict__ bB, const float* __restrict__ bV,
    u16* __restrict__ Wcat, u16* __restrict__ wRb, u16* __restrict__ wAtb,
    float* __restrict__ bcat)
{
    const int tid = blockIdx.x * 256 + threadIdx.x;
    if (tid < 262144) {
        Wcat[262144 + tid] = f2bf(wB[tid]);                    // rows 512..1023
    } else if (tid < 524288) {
        Wcat[262144 + tid] = f2bf(wV[tid - 262144]);           // rows 1024..1535
    } else if (tid < 786432) {
        wRb[tid - 524288] = f2bf(wR[tid - 524288]);
    } else if (tid < 1048576) {
        const int i = tid - 786432;                            // i = c*512 + cin
        wAtb[(i & 511) * 512 + (i >> 9)] = f2bf(wA[i]);        // wA^T
    } else if (tid < 1048576 + 1536) {
        const int j = tid - 1048576;
        bcat[j] = (j < 512) ? 0.f : (j < 1024) ? bB[j - 512] : bV[j - 1024];
    }
}

// wRbA[o] = sum_c wR[o,c]*bA[c], fp32. One wave per o, 4 waves/block.
__global__ __launch_bounds__(256) void compute_wrba(
    const float* __restrict__ wR, const float* __restrict__ bA,
    float* __restrict__ wRbA)
{
    const int o    = blockIdx.x * 4 + (threadIdx.x >> 6);
    const int lane = threadIdx.x & 63;
    float a = 0.f;
#pragma unroll
    for (int c = lane; c < 512; c += 64) a += wR[o * 512 + c] * bA[c];
#pragma unroll
    for (int off = 32; off > 0; off >>= 1) a += __shfl_down(a, off);
    if (lane == 0) wRbA[o] = a;
}

// ---------------------------------------------------------------------------
// Row softmax STATS over rows 512..1535 of each batch's [1536,1024] Y:
// stats[b][j] = {max, 1/sum} for Y row 512+j. Same reduction sequence as the
// old in-place softmax (bit-identical downstream values). Read-only on Y.
// ---------------------------------------------------------------------------
__global__ __launch_bounds__(256) void softmax_stats(
    const u16* __restrict__ Y, float2* __restrict__ stats)
{
    const u16* row = Y + (long)blockIdx.y * (1536 * 1024) + (long)(512 + blockIdx.x) * 1024;
    const int t = threadIdx.x;
    ushort4 u = ((const ushort4*)row)[t];
    float v0 = bf2f(u.x), v1 = bf2f(u.y), v2 = bf2f(u.z), v3 = bf2f(u.w);

    float m = fmaxf(fmaxf(v0, v1), fmaxf(v2, v3));
#pragma unroll
    for (int off = 32; off > 0; off >>= 1) m = fmaxf(m, __shfl_down(m, off));

    __shared__ float smax[4];
    __shared__ float ssum[4];
    const int w = t >> 6, lane = t & 63;
    if (lane == 0) smax[w] = m;
    __syncthreads();
    m = fmaxf(fmaxf(smax[0], smax[1]), fmaxf(smax[2], smax[3]));

    float e0 = __expf(v0 - m), e1 = __expf(v1 - m);
    float e2 = __expf(v2 - m), e3 = __expf(v3 - m);
    float s = e0 + e1 + e2 + e3;
#pragma unroll
    for (int off = 32; off > 0; off >>= 1) s += __shfl_down(s, off);
    if (lane == 0) ssum[w] = s;
    __syncthreads();
    if (t == 0) {
        float2 r;
        r.x = m;
        r.y = 1.0f / (ssum[0] + ssum[1] + ssum[2] + ssum[3]);
        stats[(long)blockIdx.y * 1024 + blockIdx.x] = r;
    }
}

// ---------------------------------------------------------------------------
extern "C" void kernel_launch(void* const* d_in, const int* in_sizes, int n_in,
                              void* d_out, int out_size, void* d_ws, size_t ws_size,
                              hipStream_t stream)
{
    (void)in_sizes; (void)n_in; (void)out_size; (void)ws_size;
    const float* x  = (const float*)d_in[0];
    const float* wA = (const float*)d_in[1];
    const float* bA = (const float*)d_in[2];
    const float* wB = (const float*)d_in[3];
    const float* bB = (const float*)d_in[4];
    const float* wV = (const float*)d_in[5];
    const float* bV = (const float*)d_in[6];
    const float* wR = (const float*)d_in[7];
    const float* bR = (const float*)d_in[8];
    float* out = (float*)d_out;

    const int B = 32;
    const long sY = (long)1536 * 1024;   // per-batch Y stride (bf16 elems)

    // workspace carve-up (~116 MB)
    char* p = (char*)d_ws;
    u16*   Y    = (u16*)p;   p += (long)B * sY * 2;          // 96 MB  [A';Bm;Vm] (RAW)
    u16*   H    = (u16*)p;   p += (long)B * 512 * 512 * 2;   // 16 MB  H [o,d]
    u16*   Wcat = (u16*)p;   p += (long)1536 * 512 * 2;      // [M1;wB;wV]
    u16*   wRb  = (u16*)p;   p += (long)512 * 512 * 2;
    u16*   wAtb = (u16*)p;   p += (long)512 * 512 * 2;       // wA^T bf16
    float* bcat = (float*)p; p += 1536 * 4;
    float* svec = (float*)p; p += (long)B * 1024 * 4;        // colsum of attnV
    float* wRbA = (float*)p; p += 512 * 4;
    float2* rowstats = (float2*)p; p += (long)B * 1024 * sizeof(float2); // 256 KB

    // Xt (bf16 [b,1024,512], 33.5 MB) lives in d_out — dead before final GEMM
    u16* Xt = (u16*)d_out;
    // Vt reuses Y's A'-region after the H-GEMM consumed A'
    u16* Vt = Y;                        // [1024,512] per batch, stride sY

    // 0. casts + tiny precomputes
    cast_transpose_x<<<dim3(16, 8, B), 256, 0, stream>>>(x, Xt);
    cast_weights<<<dim3(4103), 256, 0, stream>>>(wA, wB, wV, wR, bB, bV,
                                                 Wcat, wRb, wAtb, bcat);
    compute_wrba<<<dim3(128), 256, 0, stream>>>(wR, bA, wRbA);
    hipMemsetAsync(svec, 0, (long)B * 1024 * 4, stream);

    // 1. M1 = wR*wA -> Wcat rows 0..511   (NT: A=wRb[512,512], B=wAtb[512,512])
    gemm_nt<128, false, false><<<dim3(4, 4, 1), 256, 0, stream>>>(
        wRb, wAtb, Wcat, nullptr, 512, 512, 0, 0, 0);

    // 2. Y[b] = Wcat * X[b] + bcat   (rows 0..511 = A' = M1*X, no bias)
    //    batch-colocated XCD swizzle, 1D grid 768
    gemm2_y<<<dim3(768), 512, 0, stream>>>(Wcat, Xt, Y, bcat);

    // 3. softmax row-stats only (Y stays raw; consumers normalize on the fly)
    softmax_stats<<<dim3(1024, B), 256, 0, stream>>>(Y, rowstats);

    // 4. H[b][o,d] = sum_n A'[o,n]*softmax(Bm)[d,n]  (NT, K=1024; fused-softmax B)
    gemm_nt_swz<128, false, false, false, true><<<dim3(512), 256, 0, stream>>>(
        Y, Y + (long)512 * 1024, H, nullptr, 512, 1024,
        sY, sY, (long)512 * 512, 4, 16, nullptr, nullptr, rowstats);

    // 5. Vt[b] = softmax(Vm)[b]^T + colsum s   (A'-region of Y is dead now)
    transpose_colsum<<<dim3(16, 8, B), 256, 0, stream>>>(
        Y + (long)1024 * 1024, Vt, svec, sY, sY, rowstats);

    // 6. out[b][o,n] = sum_d H[o,d]*Vt[n,d] + wRbA[o]*s[n] + bR[o]  (fp32 out)
    gemm_nt_swz<128, true, true, true, false><<<dim3(1024), 256, 0, stream>>>(
        H, Vt, out, bR, 1024, 512, (long)512 * 512, sY, (long)512 * 1024,
        8, 32, svec, wRbA, nullptr);
}

// Round 5
// 297.256 us; speedup vs baseline: 1.0489x; 1.0489x over previous
//
#include <hip/hip_runtime.h>
#include <stdint.h>

typedef unsigned short u16;
typedef __bf16  bf16x8 __attribute__((ext_vector_type(8)));
typedef float   f32x4  __attribute__((ext_vector_type(4)));

__device__ __forceinline__ u16 f2bf(float f) {
    union { float f; unsigned u; } c; c.f = f;
    unsigned r = c.u + 0x7fffu + ((c.u >> 16) & 1u);   // RNE, finite inputs
    return (u16)(r >> 16);
}
__device__ __forceinline__ float bf2f(u16 b) {
    union { unsigned u; float f; } c; c.u = ((unsigned)b) << 16; return c.f;
}

// async 16B global->LDS. Generic LDS ptr: low 32 bits are the LDS offset on gfx9+.
__device__ __forceinline__ void g2l16(const u16* g, u16* l) {
    __builtin_amdgcn_global_load_lds(
        (__attribute__((address_space(1))) void*)(uintptr_t)g,
        (__attribute__((address_space(3))) void*)(uint32_t)(uintptr_t)l,
        16, 0, 0);
}

// ---------------------------------------------------------------------------
// NT GEMM core (bf16 in, fp32 acc): C[m,n] = sum_k A[m,k]*B[n,k]
//   (+ bias[m]) (+ wRbA[m]*svec[n] rank-1 term if EPI).
// A,B row-major bf16, ld == K. Tile TM x 128, BK=64, 256 thr = 4 waves (2x2).
// LDS XOR-swizzle: physical 16B chunk = logical ^ (row&7) -> conflict-free.
// Pure async staging on both operands (R4's exp-in-staging reverted: it made
// the B-path VALU-bound and lost global_load_lds — net regression).
// ---------------------------------------------------------------------------
template <int TM, bool HAS_BIAS, bool OUT_F32, bool EPI>
__device__ __forceinline__ void gemm_core(
    const u16* __restrict__ Ab, const u16* __restrict__ Bb, void* __restrict__ C,
    const float* __restrict__ bias, int N, int K, long cbase, int m0, int n0,
    const float* __restrict__ svec, const float* __restrict__ wRbA)
{
    constexpr int MI = TM / 32;
    constexpr int NA = TM / 32;
    __shared__ __align__(16) u16 As[TM * 64];
    __shared__ __align__(16) u16 Bs[128 * 64];

    const int t = threadIdx.x;
    const int w = t >> 6, lane = t & 63;
    const int wr = w >> 1, wc = w & 1;

    f32x4 acc[MI][4];
    const f32x4 zero = {0.f, 0.f, 0.f, 0.f};
#pragma unroll
    for (int i = 0; i < MI; ++i)
#pragma unroll
        for (int j = 0; j < 4; ++j) acc[i][j] = zero;

    int  aslot[NA]; long aoff[NA];
#pragma unroll
    for (int i = 0; i < NA; ++i) {
        const int s   = i * 256 + t;
        const int row = s >> 3;
        const int col = ((s & 7) ^ (row & 7)) * 8;
        aslot[i] = s * 8;
        aoff[i]  = (long)(m0 + row) * K + col;
    }
    int  bslot[4]; long boff[4];
#pragma unroll
    for (int i = 0; i < 4; ++i) {
        const int s   = i * 256 + t;
        const int row = s >> 3;
        const int col = ((s & 7) ^ (row & 7)) * 8;
        bslot[i] = s * 8;
        boff[i]  = (long)(n0 + row) * K + col;
    }

    const int fr = lane & 15;
    const int q  = lane >> 4;
    const int o0 = ((q ^ (fr & 7)) * 8);   // kh=0; kh=1 is o0 ^ 32
    const u16* fa = &As[(wr * (TM / 2) + fr) * 64];
    const u16* fb = &Bs[(wc * 64 + fr) * 64];

    for (int k0 = 0; k0 < K; k0 += 64) {
#pragma unroll
        for (int i = 0; i < NA; ++i) g2l16(Ab + aoff[i] + k0, &As[aslot[i]]);
#pragma unroll
        for (int i = 0; i < 4; ++i)  g2l16(Bb + boff[i] + k0, &Bs[bslot[i]]);
        __syncthreads();

#pragma unroll
        for (int kh = 0; kh < 2; ++kh) {
            const int o = o0 ^ (kh * 32);
            bf16x8 af[MI], bv[4];
#pragma unroll
            for (int mi = 0; mi < MI; ++mi) af[mi] = *(const bf16x8*)(fa + mi * 1024 + o);
#pragma unroll
            for (int ni = 0; ni < 4; ++ni)  bv[ni] = *(const bf16x8*)(fb + ni * 1024 + o);
#pragma unroll
            for (int mi = 0; mi < MI; ++mi)
#pragma unroll
                for (int ni = 0; ni < 4; ++ni)
                    acc[mi][ni] = __builtin_amdgcn_mfma_f32_16x16x32_bf16(
                        af[mi], bv[ni], acc[mi][ni], 0, 0, 0);
        }
        __syncthreads();
    }

    // C/D layout (m89-verified): col = lane&15, row = (lane>>4)*4 + reg
    const int ccol  = n0 + wc * 64 + fr;
    const int crow0 = m0 + wr * (TM / 2) + (lane >> 4) * 4;
    float se[4];
    if (EPI) {
#pragma unroll
        for (int ni = 0; ni < 4; ++ni) se[ni] = svec[ccol + ni * 16];
    }
#pragma unroll
    for (int mi = 0; mi < MI; ++mi) {
#pragma unroll
        for (int r = 0; r < 4; ++r) {
            const int row = crow0 + mi * 16 + r;
            float add = HAS_BIAS ? bias[row] : 0.f;
            float rk  = EPI ? wRbA[row] : 0.f;
#pragma unroll
            for (int ni = 0; ni < 4; ++ni) {
                float v = acc[mi][ni][r] + add;
                if (EPI) v += rk * se[ni];
                const long idx = cbase + (long)row * N + ccol + ni * 16;
                if (OUT_F32) ((float*)C)[idx] = v;
                else         ((u16*)C)[idx]   = f2bf(v);
            }
        }
    }
}

// 3D-grid variant (GEMM1): blockIdx = (n-blk, m-blk, batch)
template <int TM, bool HAS_BIAS, bool OUT_F32>
__global__ __launch_bounds__(256) void gemm_nt(
    const u16* __restrict__ A, const u16* __restrict__ B, void* __restrict__ C,
    const float* __restrict__ bias, int N, int K, long sA, long sB, long sC)
{
    const int bz = blockIdx.z;
    gemm_core<TM, HAS_BIAS, OUT_F32, false>(
        A + (long)bz * sA, B + (long)bz * sB, C, bias, N, K,
        (long)bz * sC, blockIdx.y * TM, blockIdx.x * 128, nullptr, nullptr);
}

// 1D-grid XCD-swizzled variant (GEMM4 / GEMM6): batch b lands on XCD b%8
template <int TM, bool HAS_BIAS, bool OUT_F32, bool EPI>
__global__ __launch_bounds__(256) void gemm_nt_swz(
    const u16* __restrict__ A, const u16* __restrict__ B, void* __restrict__ C,
    const float* __restrict__ bias, int N, int K, long sA, long sB, long sC,
    int bxn, int bpb, const float* __restrict__ s_all,
    const float* __restrict__ wRbA)
{
    const int blk  = blockIdx.x;
    const int xcd  = blk & 7;
    const int slot = blk >> 3;
    const int b    = xcd + 8 * (slot / bpb);
    const int wi   = slot % bpb;
    const int bx   = wi % bxn;
    const int by   = wi / bxn;
    gemm_core<TM, HAS_BIAS, OUT_F32, EPI>(
        A + (long)b * sA, B + (long)b * sB, C, bias, N, K,
        (long)b * sC, by * TM, bx * 128,
        EPI ? s_all + (long)b * 1024 : nullptr, wRbA);
}

// ---------------------------------------------------------------------------
// GEMM2 (Y = Wcat * Xt^T + bcat), 256x256 tile, 512 thr = 8 waves (2x4),
// BK=32, 4 LDS buffers (128 KiB), 2-tiles-ahead prefetch, counted vmcnt(4),
// batch-colocated XCD map (1D grid 768 = 8 XCD x 96, bijective). Schedule
// variants measured flat (64-66 µs) -> kept simplest (fat-region) form.
// ---------------------------------------------------------------------------
__global__ __launch_bounds__(512) void gemm2_y(
    const u16* __restrict__ A,      // Wcat [1536,512]
    const u16* __restrict__ B,      // Xt   [b][1024,512]
    u16* __restrict__ C,            // Y    [b][1536,1024]
    const float* __restrict__ bias) // bcat [1536]
{
    constexpr int K    = 512;
    constexpr int NT   = K / 32;          // 16 K-tiles
    constexpr int AREG = 256 * 32;        // u16 per operand region (8192)
    constexpr int BUFQ = 2 * AREG;        // u16 per buffer (A+B)
    __shared__ __align__(16) u16 lds[4 * BUFQ];   // 128 KiB

    const int blk  = blockIdx.x;
    const int xcd  = blk & 7;
    const int slot = blk >> 3;
    const int bz   = xcd + 8 * (slot / 24);
    const int wi   = slot % 24;
    const int m0   = (wi >> 2) * 256;     // 6 m-blocks
    const int n0   = (wi & 3) * 256;      // 4 n-blocks

    const u16* Ab = A;
    const u16* Bb = B + (long)bz * (1024 * 512);
    u16*       Cb = C + (long)bz * ((long)1536 * 1024);

    const int t    = threadIdx.x;
    const int w    = t >> 6, lane = t & 63;
    const int wr   = w >> 2, wc = w & 3;          // wave grid 2(M) x 4(N)
    const int fr   = lane & 15, q = lane >> 4;

    // ---- staging map: 1024 16B-chunks per operand per K-tile; 2/thread ----
    int  aslot[2]; long agoff[2], bgoff[2];
#pragma unroll
    for (int i = 0; i < 2; ++i) {
        const int ci  = i * 512 + t;
        const int row = ci >> 2;
        const int gc  = (ci & 3) ^ ((row >> 1) & 3);   // inverse == forward (XOR)
        aslot[i] = ci * 8;                             // linear u16 LDS slot
        agoff[i] = (long)(m0 + row) * K + gc * 8;
        bgoff[i] = (long)(n0 + row) * K + gc * 8;
    }

    // ---- fragment read offsets (u16): row*32 + chunk*8 ----
    const int rchunk = (q ^ ((fr >> 1) & 3)) * 8;
    const int abase  = (wr * 128 + fr) * 32 + rchunk;   // + mi*512
    const int bbase  = (wc * 64  + fr) * 32 + rchunk;   // + ni*512

    f32x4 acc[8][4];
    const f32x4 zero = {0.f, 0.f, 0.f, 0.f};
#pragma unroll
    for (int i = 0; i < 8; ++i)
#pragma unroll
        for (int j = 0; j < 4; ++j) acc[i][j] = zero;

    // ---- prologue: stage tiles 0 and 1 (A0,B0,A1,B1 -> 8 loads/thread) ----
#pragma unroll
    for (int i = 0; i < 2; ++i) g2l16(Ab + agoff[i],        &lds[aslot[i]]);
#pragma unroll
    for (int i = 0; i < 2; ++i) g2l16(Bb + bgoff[i],        &lds[AREG + aslot[i]]);
#pragma unroll
    for (int i = 0; i < 2; ++i) g2l16(Ab + agoff[i] + 32,   &lds[BUFQ + aslot[i]]);
#pragma unroll
    for (int i = 0; i < 2; ++i) g2l16(Bb + bgoff[i] + 32,   &lds[BUFQ + AREG + aslot[i]]);
    asm volatile("s_waitcnt vmcnt(4)" ::: "memory");   // tile 0 landed; tile 1 in flight
    __builtin_amdgcn_s_barrier();
    asm volatile("" ::: "memory");                     // no hoists above barrier

#pragma unroll
    for (int kt = 0; kt < NT; ++kt) {
        const u16* Abuf = &lds[(kt & 3) * BUFQ];           // constexpr (unrolled)
        const u16* Bbuf = Abuf + AREG;
        u16* dst = &lds[((kt + 2) & 3) * BUFQ];
        const long kg = (long)(kt + 2) * 32;

        // ---- fat region: reads + stage + MFMA, compiler-scheduled ----
        bf16x8 av[8], bv[4];
#pragma unroll
        for (int mi = 0; mi < 8; ++mi) av[mi] = *(const bf16x8*)(Abuf + abase + mi * 512);
#pragma unroll
        for (int ni = 0; ni < 4; ++ni) bv[ni] = *(const bf16x8*)(Bbuf + bbase + ni * 512);
        if (kt + 2 < NT) {                                 // constexpr (unrolled)
#pragma unroll
            for (int i = 0; i < 2; ++i) g2l16(Ab + agoff[i] + kg, dst + aslot[i]);
#pragma unroll
            for (int i = 0; i < 2; ++i) g2l16(Bb + bgoff[i] + kg, dst + AREG + aslot[i]);
        }
#pragma unroll
        for (int mi = 0; mi < 8; ++mi)
#pragma unroll
            for (int ni = 0; ni < 4; ++ni)
                acc[mi][ni] = __builtin_amdgcn_mfma_f32_16x16x32_bf16(
                    av[mi], bv[ni], acc[mi][ni], 0, 0, 0);

        // ---- tile boundary: counted wait (tile kt+1 landed; kt+2 in flight) ----
        if (kt + 1 < NT) {
            if (kt + 2 < NT) asm volatile("s_waitcnt vmcnt(4)" ::: "memory");
            else             asm volatile("s_waitcnt vmcnt(0)" ::: "memory");
            __builtin_amdgcn_s_barrier();
            asm volatile("" ::: "memory");                 // no hoists above barrier
        }
    }

    // ---- epilogue: col = lane&15, row = (lane>>4)*4 + reg ----
    const int ccol  = n0 + wc * 64 + fr;
    const int crow0 = m0 + wr * 128 + q * 4;
#pragma unroll
    for (int mi = 0; mi < 8; ++mi) {
#pragma unroll
        for (int r = 0; r < 4; ++r) {
            const int row = crow0 + mi * 16 + r;
            const float add = bias[row];
#pragma unroll
            for (int ni = 0; ni < 4; ++ni)
                Cb[(long)row * 1024 + ccol + ni * 16] = f2bf(acc[mi][ni][r] + add);
        }
    }
}

// ---------------------------------------------------------------------------
// x fp32 [b,512,1024] -> Xt bf16 [b,1024,512] (cast + transpose, 64x64 tiles)
// ---------------------------------------------------------------------------
__global__ __launch_bounds__(256) void cast_transpose_x(
    const float* __restrict__ in, u16* __restrict__ out)
{
    __shared__ u16 tile[64][68];
    const int bz = blockIdx.z;
    const float* ip = in  + (long)bz * (512 * 1024);
    u16*         op = out + (long)bz * (1024 * 512);
    const int c0 = blockIdx.x * 64;
    const int r0 = blockIdx.y * 64;
    const int tx = threadIdx.x & 15;
    const int ty = threadIdx.x >> 4;
#pragma unroll
    for (int p = 0; p < 4; ++p) {
        const int row = ty + 16 * p;
        float4 v = *(const float4*)(ip + (long)(r0 + row) * 1024 + c0 + 4 * tx);
        ushort4 o;
        o.x = f2bf(v.x); o.y = f2bf(v.y); o.z = f2bf(v.z); o.w = f2bf(v.w);
        *(ushort4*)&tile[row][4 * tx] = o;
    }
    __syncthreads();
#pragma unroll
    for (int p = 0; p < 4; ++p) {
        const int orow = ty + 16 * p;
        ushort4 o;
        o.x = tile[4 * tx + 0][orow];
        o.y = tile[4 * tx + 1][orow];
        o.z = tile[4 * tx + 2][orow];
        o.w = tile[4 * tx + 3][orow];
        *(ushort4*)&op[(long)(c0 + orow) * 512 + r0 + 4 * tx] = o;
    }
}

// ---------------------------------------------------------------------------
// Vm RAW [d,n] -> attnV^T = Vt [n,d] per batch (softmax applied on the fly
// from rowstats), PLUS column-sum s[b,n] += sum_d attnV[d,n] (s pre-zeroed).
// Bit-identical to materialized softmax: f2bf(exp(v - m_row) * inv_row).
// ---------------------------------------------------------------------------
__global__ __launch_bounds__(256) void transpose_colsum(
    const u16* __restrict__ in, u16* __restrict__ out, float* __restrict__ s,
    long sIn, long sOut, const float2* __restrict__ stats_all)
{
    __shared__ u16 tile[64][68];
    const int bz = blockIdx.z;
    const u16* ip = in  + (long)bz * sIn;
    u16*       op = out + (long)bz * sOut;
    const int c0 = blockIdx.x * 64;   // n
    const int r0 = blockIdx.y * 64;   // d
    const int t  = threadIdx.x;
    const int tx = t & 15;
    const int ty = t >> 4;
#pragma unroll
    for (int p = 0; p < 4; ++p) {
        const int row = ty + 16 * p;
        const float2 st = stats_all[(long)bz * 1024 + 512 + r0 + row];
        ushort4 v = *(const ushort4*)(ip + (long)(r0 + row) * 1024 + c0 + 4 * tx);
        ushort4 o;
        o.x = f2bf(__expf(bf2f(v.x) - st.x) * st.y);
        o.y = f2bf(__expf(bf2f(v.y) - st.x) * st.y);
        o.z = f2bf(__expf(bf2f(v.z) - st.x) * st.y);
        o.w = f2bf(__expf(bf2f(v.w) - st.x) * st.y);
        *(ushort4*)&tile[row][4 * tx] = o;
    }
    __syncthreads();
#pragma unroll
    for (int p = 0; p < 4; ++p) {
        const int orow = ty + 16 * p;
        ushort4 o;
        o.x = tile[4 * tx + 0][orow];
        o.y = tile[4 * tx + 1][orow];
        o.z = tile[4 * tx + 2][orow];
        o.w = tile[4 * tx + 3][orow];
        *(ushort4*)&op[(long)(c0 + orow) * 512 + r0 + 4 * tx] = o;
    }
    if (t < 64) {
        float a = 0.f;
#pragma unroll 8
        for (int d = 0; d < 64; ++d) a += bf2f(tile[d][t]);
        atomicAdd(&s[(long)bz * 1024 + c0 + t], a);
    }
}

// ---------------------------------------------------------------------------
// prep_weights = cast_weights + compute_wrba + svec zero, one launch.
//  blocks 0..4102   : weight casts / bcat (original cast_weights body)
//  blocks 4103..4230: wRbA[o] = sum_c wR[o,c]*bA[c]  (4 waves -> 4 o/block)
//  blocks 4231..4358: svec = 0  (32*1024 floats)
// ---------------------------------------------------------------------------
__global__ __launch_bounds__(256) void prep_weights(
    const float* __restrict__ wA, const float* __restrict__ wB,
    const float* __restrict__ wV, const float* __restrict__ wR,
    const float* __restrict__ bA, const float* __restrict__ bB,
    const float* __restrict__ bV,
    u16* __restrict__ Wcat, u16* __restrict__ wRb, u16* __restrict__ wAtb,
    float* __restrict__ bcat, float* __restrict__ wRbA,
    float* __restrict__ svec)
{
    const int blk = blockIdx.x;
    if (blk < 4103) {
        const int tid = blk * 256 + threadIdx.x;
        if (tid < 262144) {
            Wcat[262144 + tid] = f2bf(wB[tid]);                    // rows 512..1023
        } else if (tid < 524288) {
            Wcat[262144 + tid] = f2bf(wV[tid - 262144]);           // rows 1024..1535
        } else if (tid < 786432) {
            wRb[tid - 524288] = f2bf(wR[tid - 524288]);
        } else if (tid < 1048576) {
            const int i = tid - 786432;                            // i = c*512 + cin
            wAtb[(i & 511) * 512 + (i >> 9)] = f2bf(wA[i]);        // wA^T
        } else if (tid < 1048576 + 1536) {
            const int j = tid - 1048576;
            bcat[j] = (j < 512) ? 0.f : (j < 1024) ? bB[j - 512] : bV[j - 1024];
        }
    } else if (blk < 4231) {
        const int o    = (blk - 4103) * 4 + (threadIdx.x >> 6);
        const int lane = threadIdx.x & 63;
        float a = 0.f;
#pragma unroll
        for (int c = lane; c < 512; c += 64) a += wR[o * 512 + c] * bA[c];
#pragma unroll
        for (int off = 32; off > 0; off >>= 1) a += __shfl_down(a, off);
        if (lane == 0) wRbA[o] = a;
    } else {
        const int idx = (blk - 4231) * 256 + threadIdx.x;          // < 32768
        svec[idx] = 0.f;
    }
}

// ---------------------------------------------------------------------------
// softmax_apply over Y rows 512..1535 of each batch:
//  j = blockIdx.x in [0,1024); row = 512+j.
//  j <  512 (Bm rows): full softmax -> attnM[b][j][*]  (separate buffer)
//  j >= 512 (Vm rows): stats {max, 1/sum} -> rowstats[b][j] (for t_colsum)
// Same reduction sequence as the original in-place softmax.
// ---------------------------------------------------------------------------
__global__ __launch_bounds__(256) void softmax_apply(
    const u16* __restrict__ Y, u16* __restrict__ attnM,
    float2* __restrict__ stats)
{
    const int j  = blockIdx.x;
    const int bz = blockIdx.y;
    const u16* row = Y + (long)bz * (1536 * 1024) + (long)(512 + j) * 1024;
    const int t = threadIdx.x;
    ushort4 u = ((const ushort4*)row)[t];
    float v0 = bf2f(u.x), v1 = bf2f(u.y), v2 = bf2f(u.z), v3 = bf2f(u.w);

    float m = fmaxf(fmaxf(v0, v1), fmaxf(v2, v3));
#pragma unroll
    for (int off = 32; off > 0; off >>= 1) m = fmaxf(m, __shfl_down(m, off));

    __shared__ float smax[4];
    __shared__ float ssum[4];
    const int w = t >> 6, lane = t & 63;
    if (lane == 0) smax[w] = m;
    __syncthreads();
    m = fmaxf(fmaxf(smax[0], smax[1]), fmaxf(smax[2], smax[3]));

    float e0 = __expf(v0 - m), e1 = __expf(v1 - m);
    float e2 = __expf(v2 - m), e3 = __expf(v3 - m);
    float s = e0 + e1 + e2 + e3;
#pragma unroll
    for (int off = 32; off > 0; off >>= 1) s += __shfl_down(s, off);
    if (lane == 0) ssum[w] = s;
    __syncthreads();
    const float inv = 1.0f / (ssum[0] + ssum[1] + ssum[2] + ssum[3]);

    if (j < 512) {
        ushort4 o;
        o.x = f2bf(e0 * inv); o.y = f2bf(e1 * inv);
        o.z = f2bf(e2 * inv); o.w = f2bf(e3 * inv);
        ((ushort4*)(attnM + (long)bz * (512 * 1024) + (long)j * 1024))[t] = o;
    } else if (t == 0) {
        float2 r; r.x = m; r.y = inv;
        stats[(long)bz * 1024 + j] = r;
    }
}

// ---------------------------------------------------------------------------
extern "C" void kernel_launch(void* const* d_in, const int* in_sizes, int n_in,
                              void* d_out, int out_size, void* d_ws, size_t ws_size,
                              hipStream_t stream)
{
    (void)in_sizes; (void)n_in; (void)out_size; (void)ws_size;
    const float* x  = (const float*)d_in[0];
    const float* wA = (const float*)d_in[1];
    const float* bA = (const float*)d_in[2];
    const float* wB = (const float*)d_in[3];
    const float* bB = (const float*)d_in[4];
    const float* wV = (const float*)d_in[5];
    const float* bV = (const float*)d_in[6];
    const float* wR = (const float*)d_in[7];
    const float* bR = (const float*)d_in[8];
    float* out = (float*)d_out;

    const int B = 32;
    const long sY = (long)1536 * 1024;   // per-batch Y stride (bf16 elems)

    // workspace carve-up (~116 MB)
    char* p = (char*)d_ws;
    u16*   Y    = (u16*)p;   p += (long)B * sY * 2;          // 96 MB  [A';Bm;Vm] (RAW)
    u16*   H    = (u16*)p;   p += (long)B * 512 * 512 * 2;   // 16 MB  H [o,d]
    u16*   Wcat = (u16*)p;   p += (long)1536 * 512 * 2;      // [M1;wB;wV]
    u16*   wRb  = (u16*)p;   p += (long)512 * 512 * 2;
    u16*   wAtb = (u16*)p;   p += (long)512 * 512 * 2;       // wA^T bf16
    float* bcat = (float*)p; p += 1536 * 4;
    float* svec = (float*)p; p += (long)B * 1024 * 4;        // colsum of attnV
    float* wRbA = (float*)p; p += 512 * 4;
    float2* rowstats = (float2*)p; p += (long)B * 1024 * sizeof(float2); // 256 KB

    // d_out scratch: Xt bf16 [b,1024,512] at [0,32MiB) — dead after gemm2;
    // attnM bf16 [b,512,1024] at [32MiB,64MiB) — dead after gemm4.
    u16* Xt    = (u16*)d_out;
    u16* attnM = (u16*)d_out + (long)16777216;
    // Vt reuses Y's A'-region after the H-GEMM consumed A'
    u16* Vt = Y;                        // [1024,512] per batch, stride sY

    // 0. casts + tiny precomputes (one launch)
    cast_transpose_x<<<dim3(16, 8, B), 256, 0, stream>>>(x, Xt);
    prep_weights<<<dim3(4359), 256, 0, stream>>>(wA, wB, wV, wR, bA, bB, bV,
                                                 Wcat, wRb, wAtb, bcat, wRbA, svec);

    // 1. M1 = wR*wA -> Wcat rows 0..511   (NT: A=wRb[512,512], B=wAtb[512,512])
    gemm_nt<128, false, false><<<dim3(4, 4, 1), 256, 0, stream>>>(
        wRb, wAtb, Wcat, nullptr, 512, 512, 0, 0, 0);

    // 2. Y[b] = Wcat * X[b] + bcat   (rows 0..511 = A' = M1*X, no bias)
    gemm2_y<<<dim3(768), 512, 0, stream>>>(Wcat, Xt, Y, bcat);

    // 3. softmax: Bm rows materialized -> attnM; Vm rows stats -> rowstats
    softmax_apply<<<dim3(1024, B), 256, 0, stream>>>(Y, attnM, rowstats);

    // 4. H[b][o,d] = sum_n A'[o,n]*attnM[d,n]   (NT, K=1024; pure async staging)
    gemm_nt_swz<128, false, false, false><<<dim3(512), 256, 0, stream>>>(
        Y, attnM, H, nullptr, 512, 1024,
        sY, (long)512 * 1024, (long)512 * 512, 4, 16, nullptr, nullptr);

    // 5. Vt[b] = softmax(Vm)[b]^T + colsum s   (A'-region of Y is dead now)
    transpose_colsum<<<dim3(16, 8, B), 256, 0, stream>>>(
        Y + (long)1024 * 1024, Vt, svec, sY, sY, rowstats);

    // 6. out[b][o,n] = sum_d H[o,d]*Vt[n,d] + wRbA[o]*s[n] + bR[o]  (fp32 out)
    gemm_nt_swz<128, true, true, true><<<dim3(1024), 256, 0, stream>>>(
        H, Vt, out, bR, 1024, 512, (long)512 * 512, sY, (long)512 * 1024,
        8, 32, svec, wRbA);
}